// Round 1
// baseline (80.909 us; speedup 1.0000x reference)
//
#include <hip/hip_runtime.h>

typedef __attribute__((ext_vector_type(8))) __bf16 bf16x8;
typedef __attribute__((ext_vector_type(4))) float f32x4;

#define NB 8
#define NN 2048
#define NF 256
#define NU 256

static __device__ __forceinline__ unsigned short f2bf(float f) {
    union { float f; unsigned u; } a; a.f = f;
    unsigned r = a.u + 0x7FFFu + ((a.u >> 16) & 1u);   // RNE, no NaN inputs
    return (unsigned short)(r >> 16);
}

// ---------------- kernel 0: W -> MFMA B-fragment layout (bf16) ---------------
// WTf[z][kc][ub][lane][e] = W_z[kc*32 + (lane>>4)*8 + e][ub*16 + (lane&15)]
__global__ __launch_bounds__(256) void wfrag_kernel(
    const float* __restrict__ Wm, const float* __restrict__ Wu,
    unsigned short* __restrict__ WTf) {
    int idx = blockIdx.x * 256 + threadIdx.x;   // 16384 total
    int l  = idx & 63;
    int ub = (idx >> 6) & 15;
    int kc = (idx >> 10) & 7;
    int z  = idx >> 13;
    const float* W = z ? Wu : Wm;
    int u  = ub * 16 + (l & 15);
    int k0 = kc * 32 + (l >> 4) * 8;
    unsigned short p[8];
#pragma unroll
    for (int e = 0; e < 8; ++e) p[e] = f2bf(W[(k0 + e) * NU + u]);
    uint4 v;
    v.x = (unsigned)p[0] | ((unsigned)p[1] << 16);
    v.y = (unsigned)p[2] | ((unsigned)p[3] << 16);
    v.z = (unsigned)p[4] | ((unsigned)p[5] << 16);
    v.w = (unsigned)p[6] | ((unsigned)p[7] << 16);
    *(uint4*)(WTf + (size_t)idx * 8) = v;
}

// ---------------- kernel 1: h = bf16(x @ W_msg), stored in B-frag order ------
// Hf[b][ib][ub][lane][e] = h[b][ib*32 + (lane>>4)*8 + e][ub*16 + (lane&15)]
__global__ __launch_bounds__(256) void h_kernel(
    const float* __restrict__ x, const unsigned short* __restrict__ WTf,
    unsigned short* __restrict__ Hf) {
    int t = threadIdx.x;
    int w = t >> 6, l = t & 63;
    int l15 = l & 15, lh = l >> 4;
    int m0 = blockIdx.x * 64 + w * 16;
    const f32x4 fz = {0.f, 0.f, 0.f, 0.f};
    f32x4 acc[16];
#pragma unroll
    for (int i = 0; i < 16; ++i) acc[i] = fz;
    const float* xrow = x + (size_t)(m0 + l15) * NF;
#pragma unroll
    for (int kc = 0; kc < 8; ++kc) {
        int k0 = kc * 32 + lh * 8;
        float4 xa = *(const float4*)(xrow + k0);
        float4 xb = *(const float4*)(xrow + k0 + 4);
        union { unsigned short s[8]; bf16x8 v; } af;
        af.s[0] = f2bf(xa.x); af.s[1] = f2bf(xa.y);
        af.s[2] = f2bf(xa.z); af.s[3] = f2bf(xa.w);
        af.s[4] = f2bf(xb.x); af.s[5] = f2bf(xb.y);
        af.s[6] = f2bf(xb.z); af.s[7] = f2bf(xb.w);
#pragma unroll
        for (int ub = 0; ub < 16; ++ub) {
            union { uint4 q; bf16x8 v; } bf;
            bf.q = *(const uint4*)(WTf + (size_t)(kc * 1024 + ub * 64 + l) * 8);
            acc[ub] = __builtin_amdgcn_mfma_f32_16x16x32_bf16(af.v, bf.v, acc[ub], 0, 0, 0);
        }
    }
    // write Hf: lane holds D[m][u], m = m0 + lh*4 + r, u = ub*16 + l15
    int bb = m0 >> 11;            // batch
    int n0 = m0 & (NN - 1);
    int ib = n0 >> 5;
    int kl = ((n0 & 31) >> 3) + (lh >> 1);
    int e0 = (lh & 1) * 4;
#pragma unroll
    for (int ub = 0; ub < 16; ++ub) {
        unsigned short p[4];
#pragma unroll
        for (int r = 0; r < 4; ++r) p[r] = f2bf(acc[ub][r]);
        size_t off = ((size_t)((bb * 64 + ib) * 16 + ub)) * 512 + (size_t)(kl * 16 + l15) * 8 + e0;
        uint2 v;
        v.x = (unsigned)p[0] | ((unsigned)p[1] << 16);
        v.y = (unsigned)p[2] | ((unsigned)p[3] << 16);
        *(uint2*)(Hf + off) = v;
    }
}

// ---------------- kernel 2: msg GEMM + mean + fused upd GEMM + relu ----------
// per block (b, jt): out[b, j0:j0+64, :] ; 512 threads = 8 waves (wj 0..1, wu 0..3)
__global__ __launch_bounds__(512) void msg_kernel(
    const int* __restrict__ adj, const unsigned short* __restrict__ Hf,
    const float* __restrict__ x, const unsigned short* __restrict__ WTf,
    const float* __restrict__ bias, float* __restrict__ out) {
    __shared__ unsigned short Abuf[2][64 * 64];   // adj^T tile, bf16, XOR-swizzled
    __shared__ int degs[512];
    __shared__ float rdeg[64];

    int blk = blockIdx.x;
    int b = blk & 7, jt = blk >> 3;   // blk%8 = batch -> XCD-local h reuse
    int j0 = jt * 64;
    int t = threadIdx.x;
    int w = t >> 6, l = t & 63;
    int wj = w >> 2, wu = w & 3;
    int l15 = l & 15, lh = l >> 4;

    const int* adjb = adj + (size_t)b * NN * NN + j0;
    int dsum = 0;
    const f32x4 fz = {0.f, 0.f, 0.f, 0.f};
    f32x4 acc[2][4];
#pragma unroll
    for (int a = 0; a < 2; ++a)
#pragma unroll
        for (int c = 0; c < 4; ++c) acc[a][c] = fz;

    int ra[8], rb[8];

    auto LOADA = [&](int* r, int s) {
#pragma unroll
        for (int rr = 0; rr < 8; ++rr)
            r[rr] = adjb[(size_t)(s * 64 + w * 8 + rr) * NN + l];
    };
    // transpose-write: LDS byte addr for (j,i) = buf*8192 + j*128 + (i*2 ^ ((j&15)<<3))
    auto WRITEA = [&](int buf, const int* r) {
#pragma unroll
        for (int rr = 0; rr < 8; rr += 2) {
            dsum += r[rr] + r[rr + 1];
            unsigned v = ((unsigned)f2bf((float)r[rr])) |
                         (((unsigned)f2bf((float)r[rr + 1])) << 16);
            int i = w * 8 + rr;
            int off = buf * 8192 + l * 128 + ((i * 2) ^ ((l & 15) << 3));
            *(unsigned*)((char*)Abuf + off) = v;
        }
    };
    auto COMPUTE = [&](int buf, int s) {
#pragma unroll
        for (int ic = 0; ic < 2; ++ic) {
            bf16x8 afr[2];
#pragma unroll
            for (int jb = 0; jb < 2; ++jb) {
                int j = wj * 32 + jb * 16 + l15;
                int ibase = ic * 32 + lh * 8;
                union { uint2 d[2]; bf16x8 v; } aa;
                aa.d[0] = *(uint2*)((char*)Abuf + buf * 8192 + j * 128 +
                                    ((ibase * 2) ^ ((j & 15) << 3)));
                aa.d[1] = *(uint2*)((char*)Abuf + buf * 8192 + j * 128 +
                                    (((ibase + 4) * 2) ^ ((j & 15) << 3)));
                afr[jb] = aa.v;
            }
            int ib = s * 2 + ic;
#pragma unroll
            for (int ub = 0; ub < 4; ++ub) {
                int ubg = wu * 4 + ub;
                union { uint4 q; bf16x8 v; } bf;
                bf.q = *(const uint4*)(Hf + ((size_t)((b * 64 + ib) * 16 + ubg)) * 512 + l * 8);
                acc[0][ub] = __builtin_amdgcn_mfma_f32_16x16x32_bf16(afr[0], bf.v, acc[0][ub], 0, 0, 0);
                acc[1][ub] = __builtin_amdgcn_mfma_f32_16x16x32_bf16(afr[1], bf.v, acc[1][ub], 0, 0, 0);
            }
        }
    };

    LOADA(ra, 0);
    WRITEA(0, ra);
    LOADA(rb, 1);
    __syncthreads();
#pragma unroll 1
    for (int s = 0; s < 32; s += 2) {
        WRITEA(1, rb);                       // data for step s+1
        if (s + 2 < 32) LOADA(ra, s + 2);    // prefetch 2 ahead
        COMPUTE(0, s);
        __syncthreads();
        if (s + 2 < 32) WRITEA(0, ra);
        if (s + 3 < 32) LOADA(rb, s + 3);
        COMPUTE(1, s + 1);
        __syncthreads();
    }

    // degree reduce: deg[j] = sum over 8 wave-groups
    degs[t] = dsum;
    __syncthreads();
    if (t < 64) {
        int d = 0;
#pragma unroll
        for (int g = 0; g < 8; ++g) d += degs[g * 64 + t];
        rdeg[t] = d > 0 ? 1.0f / (float)d : 0.0f;
    }
    __syncthreads();

    // scale msg accumulator by 1/deg (TF segment-mean semantics: deg==0 -> 0)
#pragma unroll
    for (int jb = 0; jb < 2; ++jb) {
        int jbase = wj * 32 + jb * 16 + lh * 4;
#pragma unroll
        for (int r = 0; r < 4; ++r) {
            float sc = rdeg[jbase + r];
#pragma unroll
            for (int ub = 0; ub < 4; ++ub) acc[jb][ub][r] *= sc;
        }
    }

    // fused upd GEMM: acc += bf16(x_rows) @ W_upd (MFMA chains on C)
    const float* xb = x + ((size_t)b * NN + j0) * NF;
#pragma unroll
    for (int kc = 0; kc < 8; ++kc) {
        int k0 = kc * 32 + lh * 8;
        bf16x8 xf[2];
#pragma unroll
        for (int jb = 0; jb < 2; ++jb) {
            int j = wj * 32 + jb * 16 + l15;
            float4 xa = *(const float4*)(xb + (size_t)j * NF + k0);
            float4 xc = *(const float4*)(xb + (size_t)j * NF + k0 + 4);
            union { unsigned short sh[8]; bf16x8 v; } af;
            af.sh[0] = f2bf(xa.x); af.sh[1] = f2bf(xa.y);
            af.sh[2] = f2bf(xa.z); af.sh[3] = f2bf(xa.w);
            af.sh[4] = f2bf(xc.x); af.sh[5] = f2bf(xc.y);
            af.sh[6] = f2bf(xc.z); af.sh[7] = f2bf(xc.w);
            xf[jb] = af.v;
        }
#pragma unroll
        for (int ub = 0; ub < 4; ++ub) {
            int ubg = wu * 4 + ub;
            union { uint4 q; bf16x8 v; } bf;
            bf.q = *(const uint4*)(WTf + (size_t)(8192 + kc * 1024 + ubg * 64 + l) * 8);
            acc[0][ub] = __builtin_amdgcn_mfma_f32_16x16x32_bf16(xf[0], bf.v, acc[0][ub], 0, 0, 0);
            acc[1][ub] = __builtin_amdgcn_mfma_f32_16x16x32_bf16(xf[1], bf.v, acc[1][ub], 0, 0, 0);
        }
    }

    // epilogue: + bias, relu, store
    float* ob = out + ((size_t)b * NN + j0) * NU;
#pragma unroll
    for (int jb = 0; jb < 2; ++jb) {
#pragma unroll
        for (int ub = 0; ub < 4; ++ub) {
            int u = wu * 64 + ub * 16 + l15;
            float bv = bias[u];
            int jbase = wj * 32 + jb * 16 + lh * 4;
#pragma unroll
            for (int r = 0; r < 4; ++r) {
                float v = acc[jb][ub][r] + bv;
                ob[(size_t)(jbase + r) * NU + u] = fmaxf(v, 0.f);
            }
        }
    }
}

extern "C" void kernel_launch(void* const* d_in, const int* in_sizes, int n_in,
                              void* d_out, int out_size, void* d_ws, size_t ws_size,
                              hipStream_t stream) {
    const float* x    = (const float*)d_in[0];
    const int*   adj  = (const int*)d_in[1];
    const float* Wm   = (const float*)d_in[2];
    const float* Wu   = (const float*)d_in[3];
    const float* bias = (const float*)d_in[4];
    float* out = (float*)d_out;

    unsigned short* WTf = (unsigned short*)d_ws;                      // 256 KiB
    unsigned short* Hf  = (unsigned short*)((char*)d_ws + (1 << 18)); // 8 MiB

    wfrag_kernel<<<64, 256, 0, stream>>>(Wm, Wu, WTf);
    h_kernel<<<256, 256, 0, stream>>>(x, WTf, Hf);
    msg_kernel<<<256, 512, 0, stream>>>(adj, Hf, x, WTf, bias, out);
}

// Round 2
// 74.185 us; speedup vs baseline: 1.0906x; 1.0906x over previous
//
#include <hip/hip_runtime.h>

typedef __attribute__((ext_vector_type(8))) __bf16 bf16x8;
typedef __attribute__((ext_vector_type(4))) float f32x4;

#define NB 8
#define NN 2048
#define NF 256
#define NU 256

static __device__ __forceinline__ unsigned short f2bf(float f) {
    union { float f; unsigned u; } a; a.f = f;
    unsigned r = a.u + 0x7FFFu + ((a.u >> 16) & 1u);   // RNE, no NaN inputs
    return (unsigned short)(r >> 16);
}

// barrier WITHOUT vmcnt drain: ds-writes flushed (lgkmcnt), global loads stay in flight
static __device__ __forceinline__ void barrier_nodrain() {
    asm volatile("s_waitcnt lgkmcnt(0)" ::: "memory");
    __builtin_amdgcn_s_barrier();
    asm volatile("" ::: "memory");
}

// ---------------- kernel 0: W -> MFMA B-fragment layout (bf16) ---------------
// WTf[z][kc][ub][lane][e] = W_z[kc*32 + (lane>>4)*8 + e][ub*16 + (lane&15)]
__global__ __launch_bounds__(256) void wfrag_kernel(
    const float* __restrict__ Wm, const float* __restrict__ Wu,
    unsigned short* __restrict__ WTf) {
    int idx = blockIdx.x * 256 + threadIdx.x;   // 16384 total
    int l  = idx & 63;
    int ub = (idx >> 6) & 15;
    int kc = (idx >> 10) & 7;
    int z  = idx >> 13;
    const float* W = z ? Wu : Wm;
    int u  = ub * 16 + (l & 15);
    int k0 = kc * 32 + (l >> 4) * 8;
    unsigned short p[8];
#pragma unroll
    for (int e = 0; e < 8; ++e) p[e] = f2bf(W[(k0 + e) * NU + u]);
    uint4 v;
    v.x = (unsigned)p[0] | ((unsigned)p[1] << 16);
    v.y = (unsigned)p[2] | ((unsigned)p[3] << 16);
    v.z = (unsigned)p[4] | ((unsigned)p[5] << 16);
    v.w = (unsigned)p[6] | ((unsigned)p[7] << 16);
    *(uint4*)(WTf + (size_t)idx * 8) = v;
}

// ---------------- kernel 1: h = bf16(x @ W_msg), stored in B-frag order ------
// Hf[b][ib][ub][lane][e] = h[b][ib*32 + (lane>>4)*8 + e][ub*16 + (lane&15)]
__global__ __launch_bounds__(256) void h_kernel(
    const float* __restrict__ x, const unsigned short* __restrict__ WTf,
    unsigned short* __restrict__ Hf) {
    int t = threadIdx.x;
    int w = t >> 6, l = t & 63;
    int l15 = l & 15, lh = l >> 4;
    int m0 = blockIdx.x * 64 + w * 16;
    const f32x4 fz = {0.f, 0.f, 0.f, 0.f};
    f32x4 acc[16];
#pragma unroll
    for (int i = 0; i < 16; ++i) acc[i] = fz;
    const float* xrow = x + (size_t)(m0 + l15) * NF;
#pragma unroll
    for (int kc = 0; kc < 8; ++kc) {
        int k0 = kc * 32 + lh * 8;
        float4 xa = *(const float4*)(xrow + k0);
        float4 xb = *(const float4*)(xrow + k0 + 4);
        union { unsigned short s[8]; bf16x8 v; } af;
        af.s[0] = f2bf(xa.x); af.s[1] = f2bf(xa.y);
        af.s[2] = f2bf(xa.z); af.s[3] = f2bf(xa.w);
        af.s[4] = f2bf(xb.x); af.s[5] = f2bf(xb.y);
        af.s[6] = f2bf(xb.z); af.s[7] = f2bf(xb.w);
#pragma unroll
        for (int ub = 0; ub < 16; ++ub) {
            union { uint4 q; bf16x8 v; } bf;
            bf.q = *(const uint4*)(WTf + (size_t)(kc * 1024 + ub * 64 + l) * 8);
            acc[ub] = __builtin_amdgcn_mfma_f32_16x16x32_bf16(af.v, bf.v, acc[ub], 0, 0, 0);
        }
    }
    int bb = m0 >> 11;            // batch
    int n0 = m0 & (NN - 1);
    int ib = n0 >> 5;
    int kl = ((n0 & 31) >> 3) + (lh >> 1);
    int e0 = (lh & 1) * 4;
#pragma unroll
    for (int ub = 0; ub < 16; ++ub) {
        unsigned short p[4];
#pragma unroll
        for (int r = 0; r < 4; ++r) p[r] = f2bf(acc[ub][r]);
        size_t off = ((size_t)((bb * 64 + ib) * 16 + ub)) * 512 + (size_t)(kl * 16 + l15) * 8 + e0;
        uint2 v;
        v.x = (unsigned)p[0] | ((unsigned)p[1] << 16);
        v.y = (unsigned)p[2] | ((unsigned)p[3] << 16);
        *(uint2*)(Hf + off) = v;
    }
}

// ---------------- kernel 2: msg GEMM + mean + fused upd GEMM + relu ----------
// per block (b, jt): out[b, j0:j0+64, :] ; 512 threads = 8 waves (wj 0..1, wu 0..3)
// Software pipeline: adj 4-step register ring, Hf 1-step register prefetch,
// raw barriers (no vmcnt drain) so HBM loads stay in flight across phases.
__global__ __launch_bounds__(512) void msg_kernel(
    const int* __restrict__ adj, const unsigned short* __restrict__ Hf,
    const float* __restrict__ x, const unsigned short* __restrict__ WTf,
    const float* __restrict__ bias, float* __restrict__ out) {
    __shared__ unsigned short Abuf[2][64 * 64];   // adj^T tile, bf16, XOR-swizzled
    __shared__ int degs[512];
    __shared__ float rdeg[64];

    int blk = blockIdx.x;
    int b = blk & 7, jt = blk >> 3;   // blk%8 = batch -> XCD-local Hf reuse
    int j0 = jt * 64;
    int t = threadIdx.x;
    int w = t >> 6, l = t & 63;
    int wj = w >> 2, wu = w & 3;
    int l15 = l & 15, lh = l >> 4;

    const int* adjb = adj + (size_t)b * NN * NN + j0;
    int dsum = 0;
    const f32x4 fz = {0.f, 0.f, 0.f, 0.f};
    f32x4 acc[2][4];
#pragma unroll
    for (int a = 0; a < 2; ++a)
#pragma unroll
        for (int c = 0; c < 4; ++c) acc[a][c] = fz;

    int r0[8], r1[8], r2[8], r3[8];   // adj prefetch ring (named: rule #20)
    uint4 hc[8], hn[8];               // Hf fragment prefetch (cur / next)

    auto LOADA = [&](int* r, int s) {
#pragma unroll
        for (int rr = 0; rr < 8; ++rr)
            r[rr] = adjb[(size_t)(s * 64 + w * 8 + rr) * NN + l];
    };
    auto LOADH = [&](uint4* h, int s) {
#pragma unroll
        for (int ic = 0; ic < 2; ++ic) {
            int ib = s * 2 + ic;
#pragma unroll
            for (int ub = 0; ub < 4; ++ub) {
                int ubg = wu * 4 + ub;
                h[ic * 4 + ub] = *(const uint4*)(Hf +
                    ((size_t)((b * 64 + ib) * 16 + ubg)) * 512 + (size_t)l * 8);
            }
        }
    };
    // transpose-write: LDS byte addr for (j,i) = buf*8192 + j*128 + (i*2 ^ ((j&15)<<3))
    auto WRITEA = [&](int buf, const int* r) {
#pragma unroll
        for (int rr = 0; rr < 8; rr += 2) {
            dsum += r[rr] + r[rr + 1];
            // adj in {0,1}: packed bf16 pair = (r0 | r1<<16) * 0x3F80
            unsigned v = ((unsigned)(r[rr] | (r[rr + 1] << 16))) * 0x3F80u;
            int i = w * 8 + rr;
            int off = buf * 8192 + l * 128 + ((i * 2) ^ ((l & 15) << 3));
            *(unsigned*)((char*)Abuf + off) = v;
        }
    };
    auto COMPUTE = [&](int buf, const uint4* h) {
#pragma unroll
        for (int ic = 0; ic < 2; ++ic) {
            bf16x8 afr[2];
#pragma unroll
            for (int jb = 0; jb < 2; ++jb) {
                int j = wj * 32 + jb * 16 + l15;
                int ibase = ic * 32 + lh * 8;
                union { uint2 d[2]; bf16x8 v; } aa;
                aa.d[0] = *(uint2*)((char*)Abuf + buf * 8192 + j * 128 +
                                    ((ibase * 2) ^ ((j & 15) << 3)));
                aa.d[1] = *(uint2*)((char*)Abuf + buf * 8192 + j * 128 +
                                    (((ibase + 4) * 2) ^ ((j & 15) << 3)));
                afr[jb] = aa.v;
            }
#pragma unroll
            for (int ub = 0; ub < 4; ++ub) {
                union { uint4 q; bf16x8 v; } bf;
                bf.q = h[ic * 4 + ub];
                acc[0][ub] = __builtin_amdgcn_mfma_f32_16x16x32_bf16(afr[0], bf.v, acc[0][ub], 0, 0, 0);
                acc[1][ub] = __builtin_amdgcn_mfma_f32_16x16x32_bf16(afr[1], bf.v, acc[1][ub], 0, 0, 0);
            }
        }
    };

    // prologue: fill adj ring with steps 0..3, Hf with step 0; stage step 0
    LOADA(r0, 0); LOADA(r1, 1); LOADA(r2, 2); LOADA(r3, 3);
    LOADH(hc, 0);
    WRITEA(0, r0);
    LOADA(r0, 4);
    barrier_nodrain();

    // 8 iterations x 4 steps; buf = step&1; ring slot = step&3 (static names)
#pragma unroll 1
    for (int s4 = 0; s4 < 32; s4 += 4) {
        LOADH(hn, s4 + 1);                          // issue Hf first (FIFO order)
        WRITEA(1, r1);
        if (s4 + 5 < 32) LOADA(r1, s4 + 5);
        COMPUTE(0, hc);
        barrier_nodrain();

        LOADH(hc, s4 + 2);
        WRITEA(0, r2);
        if (s4 + 6 < 32) LOADA(r2, s4 + 6);
        COMPUTE(1, hn);
        barrier_nodrain();

        LOADH(hn, s4 + 3);
        WRITEA(1, r3);
        if (s4 + 7 < 32) LOADA(r3, s4 + 7);
        COMPUTE(0, hc);
        barrier_nodrain();

        if (s4 + 4 < 32) LOADH(hc, s4 + 4);
        WRITEA(0, r0);
        if (s4 + 8 < 32) LOADA(r0, s4 + 8);
        COMPUTE(1, hn);
        barrier_nodrain();
    }

    // degree reduce: deg[j] = sum over 8 wave-groups
    degs[t] = dsum;
    barrier_nodrain();
    if (t < 64) {
        int d = 0;
#pragma unroll
        for (int g = 0; g < 8; ++g) d += degs[g * 64 + t];
        rdeg[t] = d > 0 ? 1.0f / (float)d : 0.0f;
    }
    barrier_nodrain();

    // scale msg accumulator by 1/deg (TF segment-mean semantics: deg==0 -> 0)
#pragma unroll
    for (int jb = 0; jb < 2; ++jb) {
        int jbase = wj * 32 + jb * 16 + lh * 4;
#pragma unroll
        for (int r = 0; r < 4; ++r) {
            float sc = rdeg[jbase + r];
#pragma unroll
            for (int ub = 0; ub < 4; ++ub) acc[jb][ub][r] *= sc;
        }
    }

    // fused upd GEMM: acc += bf16(x_rows) @ W_upd (MFMA chains on C)
    const float* xb = x + ((size_t)b * NN + j0) * NF;
#pragma unroll
    for (int kc = 0; kc < 8; ++kc) {
        int k0 = kc * 32 + lh * 8;
        bf16x8 xf[2];
#pragma unroll
        for (int jb = 0; jb < 2; ++jb) {
            int j = wj * 32 + jb * 16 + l15;
            float4 xa = *(const float4*)(xb + (size_t)j * NF + k0);
            float4 xc = *(const float4*)(xb + (size_t)j * NF + k0 + 4);
            union { unsigned short sh[8]; bf16x8 v; } af;
            af.sh[0] = f2bf(xa.x); af.sh[1] = f2bf(xa.y);
            af.sh[2] = f2bf(xa.z); af.sh[3] = f2bf(xa.w);
            af.sh[4] = f2bf(xc.x); af.sh[5] = f2bf(xc.y);
            af.sh[6] = f2bf(xc.z); af.sh[7] = f2bf(xc.w);
            xf[jb] = af.v;
        }
#pragma unroll
        for (int ub = 0; ub < 4; ++ub) {
            int ubg = wu * 4 + ub;
            union { uint4 q; bf16x8 v; } bf;
            bf.q = *(const uint4*)(WTf + (size_t)(8192 + kc * 1024 + ubg * 64 + l) * 8);
            acc[0][ub] = __builtin_amdgcn_mfma_f32_16x16x32_bf16(xf[0], bf.v, acc[0][ub], 0, 0, 0);
            acc[1][ub] = __builtin_amdgcn_mfma_f32_16x16x32_bf16(xf[1], bf.v, acc[1][ub], 0, 0, 0);
        }
    }

    // epilogue: + bias, relu, store
    float* ob = out + ((size_t)b * NN + j0) * NU;
#pragma unroll
    for (int jb = 0; jb < 2; ++jb) {
#pragma unroll
        for (int ub = 0; ub < 4; ++ub) {
            int u = wu * 64 + ub * 16 + l15;
            float bv = bias[u];
            int jbase = wj * 32 + jb * 16 + lh * 4;
#pragma unroll
            for (int r = 0; r < 4; ++r) {
                float v = acc[jb][ub][r] + bv;
                ob[(size_t)(jbase + r) * NU + u] = fmaxf(v, 0.f);
            }
        }
    }
}

extern "C" void kernel_launch(void* const* d_in, const int* in_sizes, int n_in,
                              void* d_out, int out_size, void* d_ws, size_t ws_size,
                              hipStream_t stream) {
    const float* x    = (const float*)d_in[0];
    const int*   adj  = (const int*)d_in[1];
    const float* Wm   = (const float*)d_in[2];
    const float* Wu   = (const float*)d_in[3];
    const float* bias = (const float*)d_in[4];
    float* out = (float*)d_out;

    unsigned short* WTf = (unsigned short*)d_ws;                      // 256 KiB
    unsigned short* Hf  = (unsigned short*)((char*)d_ws + (1 << 18)); // 8 MiB

    wfrag_kernel<<<64, 256, 0, stream>>>(Wm, Wu, WTf);
    h_kernel<<<256, 256, 0, stream>>>(x, WTf, Hf);
    msg_kernel<<<256, 512, 0, stream>>>(adj, Hf, x, WTf, bias, out);
}